// Round 12
// baseline (336.186 us; speedup 1.0000x reference)
//
#include <hip/hip_runtime.h>

typedef unsigned short u16;
typedef __attribute__((ext_vector_type(8))) short short8;
typedef __attribute__((ext_vector_type(8))) _Float16 half8;
typedef __attribute__((ext_vector_type(4))) float f32x4;
typedef __attribute__((ext_vector_type(4))) u16 u16x4;
typedef __attribute__((ext_vector_type(4))) unsigned int u32x4;

#define DEVINL static __device__ __forceinline__

DEVINL u16 f2bf(float f) {
  unsigned u = __builtin_bit_cast(unsigned, f);
  u += 0x7fffu + ((u >> 16) & 1u);
  return (u16)(u >> 16);
}
DEVINL float bf2f(u16 h) {
  return __builtin_bit_cast(float, ((unsigned)h) << 16);
}
DEVINL u16 f2h(float f) { return __builtin_bit_cast(u16, (_Float16)f); }
DEVINL float h2f(u16 h) { return (float)__builtin_bit_cast(_Float16, h); }

// async global->LDS, 16B per lane; lds base must be wave-uniform
DEVINL void gload16(const void* g, void* l) {
  __builtin_amdgcn_global_load_lds(
      (const __attribute__((address_space(1))) void*)g,
      (__attribute__((address_space(3))) void*)l, 16, 0, 0);
}

#define BAR() asm volatile("s_barrier" ::: "memory")
#define WAIT_VMN(n) asm volatile("s_waitcnt vmcnt(" #n ")" ::: "memory")

// ---------------- converts ----------------

// hidden [S=1024,B=32,H=1024] f32 -> hf16 [B,S,H] fp16 + hT [B,H,S] bf16
// LDS transpose with XOR col-swizzle (col ^= ((s>>4)&3)<<2): read conflicts 8-way -> 2-way.
__global__ __launch_bounds__(256) void cvt_hidden2_k(const float* __restrict__ hid,
                                                     u16* __restrict__ hf,
                                                     u16* __restrict__ hT) {
  __shared__ u16 tl[64][72];
  const int s0 = blockIdx.x * 64;
  const int h0 = blockIdx.y * 64;
  const int b = blockIdx.z;
  const int t = threadIdx.x;
  const int r = t >> 4;
  const int c4 = (t & 15) * 4;
#pragma unroll
  for (int it = 0; it < 4; ++it) {
    const int s = it * 16 + r;
    const f32x4 v = *(const f32x4*)(hid + ((size_t)(s0 + s) * 32 + b) * 1024 + h0 + c4);
    u16x4 of;
    const int cs = c4 ^ (it << 2);  // (s>>4)==it here
#pragma unroll
    for (int j = 0; j < 4; ++j) {
      of[j] = f2h(v[j]);
      tl[s][cs + j] = f2bf(v[j]);
    }
    *(u16x4*)(hf + ((size_t)b * 1024 + s0 + s) * 1024 + h0 + c4) = of;
  }
  __syncthreads();
  const int h = t >> 2;
  const int sq = (t & 3) * 16;
  u16 tmp[16] __attribute__((aligned(16)));
#pragma unroll
  for (int i = 0; i < 16; ++i)
    tmp[i] = tl[sq + i][h ^ ((((sq + i) >> 4) & 3) << 2)];
  u16* dst = hT + ((size_t)b * 1024 + h0 + h) * 1024 + s0 + sq;
  *(u32x4*)(dst) = *(const u32x4*)&tmp[0];
  *(u32x4*)(dst + 8) = *(const u32x4*)&tmp[8];
}

// f32 -> split fp16 (hi, lo)
__global__ __launch_bounds__(256) void cvt_split_h_k(const float* __restrict__ in,
                                                     u16* __restrict__ hi_o,
                                                     u16* __restrict__ lo_o, long n4) {
  long i = (long)blockIdx.x * 256 + threadIdx.x;
  const long stride = (long)gridDim.x * 256;
  for (; i < n4; i += stride) {
    const f32x4 v = ((const f32x4*)in)[i];
    u16x4 oh, ol;
#pragma unroll
    for (int j = 0; j < 4; ++j) {
      const u16 hi = f2h(v[j]);
      oh[j] = hi;
      ol[j] = f2h(v[j] - h2f(hi));
    }
    ((u16x4*)hi_o)[i] = oh;
    ((u16x4*)lo_o)[i] = ol;
  }
}

// generic f32 -> bf16 (single)
__global__ __launch_bounds__(256) void cvt_f32_bf16_k(const float* __restrict__ in,
                                                      u16* __restrict__ out, long n4) {
  long i = (long)blockIdx.x * 256 + threadIdx.x;
  const long stride = (long)gridDim.x * 256;
  for (; i < n4; i += stride) {
    const f32x4 v = ((const f32x4*)in)[i];
    u16x4 o;
#pragma unroll
    for (int j = 0; j < 4; ++j) o[j] = f2bf(v[j]);
    ((u16x4*)out)[i] = o;
  }
}

// K_w [j=1024][h=1024] f32 -> transposed single fp16: out[h][j]
__global__ __launch_bounds__(256) void cvt_w_t_h_k(const float* __restrict__ in,
                                                   u16* __restrict__ out) {
  __shared__ float tile[64][65];
  const int bh = blockIdx.x * 64;
  const int bj = blockIdx.y * 64;
  const int t = threadIdx.x;
  const int r = t >> 4;
  const int c4 = (t & 15) * 4;
#pragma unroll
  for (int it = 0; it < 4; ++it) {
    const int row = it * 16 + r;
    const f32x4 v = *(const f32x4*)(in + (size_t)(bj + row) * 1024 + bh + c4);
#pragma unroll
    for (int j = 0; j < 4; ++j) tile[c4 + j][row] = v[j];
  }
  __syncthreads();
#pragma unroll
  for (int it = 0; it < 4; ++it) {
    const int hrow = it * 16 + r;
    u16x4 of;
#pragma unroll
    for (int j = 0; j < 4; ++j) of[j] = f2h(tile[hrow][c4 + j]);
    *(u16x4*)(out + (size_t)(bh + hrow) * 1024 + bj + c4) = of;
  }
}

// ---------------- 2-pass fp16 GEMM, 128x256 tile, 2 blocks/CU ----------------
// C = (Ah+Al) @ B^T.  A split fp16 (LDS pair rows 128B, chunk g=c^(r&7): g<4 hi, g>=4 lo),
// B single fp16 (LDS rows 64B, chunk g = c ^ ((r>>1)&3)).
// BM=128, BN=256, BK=32, 8 waves (2x4), wave tile 64x64, 64KB LDS (2 bufs)
// -> 2 blocks/CU: epilogue/prologue/boundary of one block overlap compute of the other.
// Sync: only {vmcnt(0); s_barrier} per K-tile (minimal-sync, r11 argument).
// CM 0: qp = x @ kwT^T, flat M=16384, fp16-split out (C0 hi, C1 lo). grid 512.
// CM 1: scores[b] = q'[b] @ hf[b]^T, batched B=32, f32 out (C0). grid 512.
template <int CM>
__global__ __launch_bounds__(512) void gemm2_8ph_k(
    const u16* __restrict__ Ah_, const u16* __restrict__ Al_,
    const u16* __restrict__ B_, void* __restrict__ C0, void* __restrict__ C1) {
  __shared__ u16 lA[2][128 * 64];  // 32 KiB
  __shared__ u16 lB[2][256 * 32];  // 32 KiB
  const int bid = blockIdx.x;
  const int swz = (bid & 7) * 64 + (bid >> 3);  // bijective on 512; XCD-chunked
  int m0, n0;
  const u16 *Ah, *Al, *Bm;
  float* Cf = nullptr;
  u16 *Chi = nullptr, *Clo = nullptr;
  if (CM == 0) {
    m0 = (swz >> 2) * 128;
    n0 = (swz & 3) * 256;
    Ah = Ah_; Al = Al_; Bm = B_;
    Chi = (u16*)C0; Clo = (u16*)C1;
  } else {
    const int z = swz >> 4;  // 2 consecutive batches per XCD group
    m0 = ((swz >> 2) & 3) * 128;
    n0 = (swz & 3) * 256;
    Ah = Ah_ + (size_t)z * 512 * 1024;
    Al = Al_ + (size_t)z * 512 * 1024;
    Bm = B_ + (size_t)z * 1024 * 1024;
    Cf = (float*)C0 + (size_t)z * 512 * 1024;
  }
  const int tid = threadIdx.x;
  const int lane = tid & 63, wid = tid >> 6;
  const int wr = wid >> 2, wc = wid & 3;     // 2 x 4 waves, wave tile 64x64
  const int fr = lane & 15, fk = lane >> 4;

  f32x4 acc[4][4] = {};

  // 2 loads/wave: A pair K-tile (1024 slots of 16B)
#define STAGEA(pb, kt)                                                         \
  {                                                                            \
    _Pragma("unroll") for (int j = 0; j < 2; ++j) {                            \
      const int slot = j * 512 + tid;                                          \
      const int r = slot >> 3;                                                 \
      const int g = (slot & 7) ^ (r & 7);                                      \
      const u16* src = (g < 4) ? Ah : Al;                                      \
      gload16(src + (size_t)(m0 + r) * 1024 + (kt) * 32 + (g & 3) * 8,         \
              &lA[pb][(j * 512 + wid * 64) * 8]);                              \
    }                                                                          \
  }
  // 2 loads/wave: B K-tile (1024 slots of 16B)
#define STAGEB(pb, kt)                                                         \
  {                                                                            \
    _Pragma("unroll") for (int j = 0; j < 2; ++j) {                            \
      const int slot = j * 512 + tid;                                          \
      const int r = slot >> 2;                                                 \
      const int g = (slot & 3) ^ ((r >> 1) & 3);                               \
      gload16(Bm + (size_t)(n0 + r) * 1024 + (kt) * 32 + g * 8,                \
              &lB[pb][(j * 512 + wid * 64) * 8]);                              \
    }                                                                          \
  }

  STAGEA(0, 0);
  STAGEB(0, 0);

  for (int t = 0; t < 32; ++t) {
    const int p = t & 1;
    WAIT_VMN(0);
    BAR();
    half8 bf[4];
#pragma unroll
    for (int nf = 0; nf < 4; ++nf) {
      const int rn = wc * 64 + nf * 16 + fr;
      const int cn = fk ^ ((rn >> 1) & 3);
      bf[nf] = *(const half8*)&lB[p][rn * 32 + cn * 8];
    }
    if (t < 31) {
      STAGEA(p ^ 1, t + 1);
      STAGEB(p ^ 1, t + 1);
    }
#pragma unroll
    for (int mf = 0; mf < 4; ++mf) {
      const int r = wr * 64 + mf * 16 + fr;
      const int ch = fk ^ (r & 7);
      const half8 ah = *(const half8*)&lA[p][r * 64 + ch * 8];
      const half8 al = *(const half8*)&lA[p][r * 64 + (ch ^ 4) * 8];
      __builtin_amdgcn_s_setprio(1);
#pragma unroll
      for (int nf = 0; nf < 4; ++nf) {
        acc[mf][nf] =
            __builtin_amdgcn_mfma_f32_16x16x32_f16(ah, bf[nf], acc[mf][nf], 0, 0, 0);
        acc[mf][nf] =
            __builtin_amdgcn_mfma_f32_16x16x32_f16(al, bf[nf], acc[mf][nf], 0, 0, 0);
      }
      __builtin_amdgcn_s_setprio(0);
    }
  }
#undef STAGEA
#undef STAGEB

  const int cb = n0 + wc * 64 + fr;
  const int rb = m0 + wr * 64 + fk * 4;
  if (CM == 0) {
#pragma unroll
    for (int mf = 0; mf < 4; ++mf)
#pragma unroll
      for (int nf = 0; nf < 4; ++nf) {
        const int col = cb + nf * 16;
#pragma unroll
        for (int j = 0; j < 4; ++j) {
          const int row = rb + mf * 16 + j;
          const float kv = acc[mf][nf][j];
          const u16 hi = f2h(kv);
          Chi[(size_t)row * 1024 + col] = hi;
          Clo[(size_t)row * 1024 + col] = f2h(kv - h2f(hi));
        }
      }
  } else {
#pragma unroll
    for (int mf = 0; mf < 4; ++mf)
#pragma unroll
      for (int nf = 0; nf < 4; ++nf) {
        const int col = cb + nf * 16;
#pragma unroll
        for (int j = 0; j < 4; ++j) {
          const int row = rb + mf * 16 + j;
          Cf[(size_t)row * 1024 + col] = acc[mf][nf][j];
        }
      }
  }
}

// ---------------- single-pass bf16 GEMM, 2-buf, 1 barrier per K-tile ----------------
// CM 0: ctx = attn[b] @ hT[b]^T, batched, bf16 out.
// CM 1: out = sigmoid(A @ Bt^T + bias), flat M=16384, f32 out.
template <int CM>
__global__ __launch_bounds__(512) void gemm1_8ph_k(
    const u16* __restrict__ A_, const u16* __restrict__ Bt_,
    const float* __restrict__ bias, void* __restrict__ Cout) {
  __shared__ u16 lds[2][2][256 * 64];  // 131072 B
  const int bid = blockIdx.x;
  const int swz = (bid & 7) * 32 + (bid >> 3);
  int m0, n0;
  const u16 *A, *Bt;
  float* Cf = nullptr;
  u16* Cb = nullptr;
  if (CM == 0) {
    const int z = swz >> 3;
    m0 = ((swz >> 2) & 1) * 256;
    n0 = (swz & 3) * 256;
    A = A_ + (size_t)z * 512 * 1024;
    Bt = Bt_ + (size_t)z * 1024 * 1024;
    Cb = (u16*)Cout + (size_t)z * 512 * 1024;
  } else {
    m0 = (swz >> 2) * 256;
    n0 = (swz & 3) * 256;
    A = A_; Bt = Bt_;
    Cf = (float*)Cout;
  }
  const int tid = threadIdx.x;
  const int lane = tid & 63, wid = tid >> 6;
  const int wr = wid >> 2, wc = wid & 3;
  const int fr = lane & 15, fk = lane >> 4;

  f32x4 acc[8][4] = {};

#define STAGE1(pb, q, gp, rb, kt)                                              \
  {                                                                            \
    _Pragma("unroll") for (int j = 0; j < 4; ++j) {                            \
      const int slot = j * 512 + tid;                                          \
      const int r = slot >> 3;                                                 \
      const int g = (slot & 7) ^ (r & 7);                                      \
      gload16((gp) + (size_t)((rb) + r) * 1024 + (kt) * 64 + g * 8,            \
              &lds[pb][q][(j * 512 + wid * 64) * 8]);                          \
    }                                                                          \
  }

  STAGE1(0, 0, A, m0, 0);
  STAGE1(0, 1, Bt, n0, 0);

  for (int t = 0; t < 16; ++t) {
    const int p = t & 1;
    WAIT_VMN(0);
    BAR();
    short8 bfr[4][2];
#pragma unroll
    for (int nf = 0; nf < 4; ++nf) {
      const int rn = wc * 64 + nf * 16 + fr;
#pragma unroll
      for (int ks = 0; ks < 2; ++ks) {
        const int g = (ks * 4 + fk) ^ (rn & 7);
        bfr[nf][ks] = *(const short8*)&lds[p][1][rn * 64 + g * 8];
      }
    }
    if (t < 15) {
      STAGE1(p ^ 1, 0, A, m0, t + 1);
      STAGE1(p ^ 1, 1, Bt, n0, t + 1);
    }
#pragma unroll
    for (int ph = 0; ph < 4; ++ph) {
      short8 a[2][2];
#pragma unroll
      for (int i = 0; i < 2; ++i) {
        const int r = wr * 128 + (ph * 2 + i) * 16 + fr;
#pragma unroll
        for (int ks = 0; ks < 2; ++ks) {
          const int g = (ks * 4 + fk) ^ (r & 7);
          a[i][ks] = *(const short8*)&lds[p][0][r * 64 + g * 8];
        }
      }
      __builtin_amdgcn_s_setprio(1);
#pragma unroll
      for (int i = 0; i < 2; ++i)
#pragma unroll
        for (int nf = 0; nf < 4; ++nf) {
          acc[ph * 2 + i][nf] = __builtin_amdgcn_mfma_f32_16x16x32_bf16(
              a[i][0], bfr[nf][0], acc[ph * 2 + i][nf], 0, 0, 0);
          acc[ph * 2 + i][nf] = __builtin_amdgcn_mfma_f32_16x16x32_bf16(
              a[i][1], bfr[nf][1], acc[ph * 2 + i][nf], 0, 0, 0);
        }
      __builtin_amdgcn_s_setprio(0);
    }
  }
#undef STAGE1

  const int cb = n0 + wc * 64 + fr;
  const int rb = m0 + wr * 128 + fk * 4;
  if (CM == 0) {
#pragma unroll
    for (int mf = 0; mf < 8; ++mf)
#pragma unroll
      for (int nf = 0; nf < 4; ++nf) {
        const int col = cb + nf * 16;
#pragma unroll
        for (int j = 0; j < 4; ++j) {
          const int row = rb + mf * 16 + j;
          Cb[(size_t)row * 1024 + col] = f2bf(acc[mf][nf][j]);
        }
      }
  } else {
#pragma unroll
    for (int mf = 0; mf < 8; ++mf)
#pragma unroll
      for (int nf = 0; nf < 4; ++nf) {
        const int col = cb + nf * 16;
        const float bv = bias[col];
#pragma unroll
        for (int j = 0; j < 4; ++j) {
          const int row = rb + mf * 16 + j;
          const float xv = acc[mf][nf][j] + bv;
          Cf[(size_t)row * 1024 + col] = 1.0f / (1.0f + __expf(-xv));
        }
      }
  }
}

// ---------------- softmax over last dim (1024), writes compact bf16 attn ----------------
__global__ __launch_bounds__(256) void softmax_k(const float* __restrict__ S,
                                                 u16* __restrict__ Attn) {
  const float* rp = S + (size_t)blockIdx.x * 1024;
  const int tid = threadIdx.x;
  const int lane = tid & 63, wid = tid >> 6;
  const f32x4 v = ((const f32x4*)rp)[tid];
  float mx = fmaxf(fmaxf(v[0], v[1]), fmaxf(v[2], v[3]));
#pragma unroll
  for (int off = 32; off; off >>= 1) mx = fmaxf(mx, __shfl_xor(mx, off));
  __shared__ float red[4];
  __shared__ float red2[4];
  if (lane == 0) red[wid] = mx;
  __syncthreads();
  mx = fmaxf(fmaxf(red[0], red[1]), fmaxf(red[2], red[3]));
  const float e0 = __expf(v[0] - mx), e1 = __expf(v[1] - mx);
  const float e2 = __expf(v[2] - mx), e3 = __expf(v[3] - mx);
  float s = (e0 + e1) + (e2 + e3);
#pragma unroll
  for (int off = 32; off; off >>= 1) s += __shfl_xor(s, off);
  if (lane == 0) red2[wid] = s;
  __syncthreads();
  const float inv = 1.0f / (red2[0] + red2[1] + red2[2] + red2[3]);
  u16x4 o;
  o[0] = f2bf(e0 * inv); o[1] = f2bf(e1 * inv); o[2] = f2bf(e2 * inv); o[3] = f2bf(e3 * inv);
  ((u16x4*)(Attn + (size_t)blockIdx.x * 1024))[tid] = o;
}

// ---------------- launch ----------------
// Shapes: S=1024, B=32, H=1024, T=512.
//   q'  = x @ K_w            (fp16 2-pass, 128x256, 2 blocks/CU; K_b dropped)
//   scr = q'[b] @ hf16[b]^T  (fp16 2-pass, 128x256, f32 out)
//   attn = softmax(scr)      (compact bf16)
//   ctx = attn[b] @ hT[b]^T  (bf16, 2-buf, 1-barrier/K-tile)
//   out = sigmoid(ctx @ V_w^T + V_b)
// ws (MB): hf16 0-64 (attn reuses 0-32) | hT 64-128 | qhi 128-160 (ctx reuses) |
//          qlo 160-192 | scores f32 192-256 | weights 256-260
extern "C" void kernel_launch(void* const* d_in, const int* in_sizes, int n_in,
                              void* d_out, int out_size, void* d_ws, size_t ws_size,
                              hipStream_t stream) {
  const float* hidden = (const float*)d_in[0];
  const float* x = (const float*)d_in[1];
  // d_in[2] problem_q unused; d_in[4] K_b dropped (softmax shift invariance)
  const float* K_w = (const float*)d_in[3];
  const float* V_w = (const float*)d_in[5];
  const float* V_b = (const float*)d_in[6];

  char* ws = (char*)d_ws;
  u16* hf16 = (u16*)(ws);
  u16* hT = (u16*)(ws + 67108864);
  u16* qhi = (u16*)(ws + 134217728);
  u16* qlo = (u16*)(ws + 167772160);
  float* scoresF = (float*)(ws + 201326592);
  u16* attn = hf16;  // reuse (hf16 dead after scores)
  u16* ctx = qhi;    // reuse (q' dead after scores)
  u16* kwT = (u16*)(ws + 268435456);
  u16* vw = kwT + 1024 * 1024;
  u16* xhi = (u16*)d_out;
  u16* xlo = xhi + 32L * 512 * 1024;
  float* out = (float*)d_out;

  // 1. hidden [S,B,H] -> fp16 [B,S,H] + transposed bf16 [B,H,S]
  cvt_hidden2_k<<<dim3(16, 16, 32), 256, 0, stream>>>(hidden, hf16, hT);
  // 2. x -> split fp16 (into d_out; dead before final GEMM overwrites it)
  cvt_split_h_k<<<2048, 256, 0, stream>>>(x, xhi, xlo, 32L * 512 * 1024 / 4);
  // 3. weights: K_w transposed fp16, V_w bf16
  cvt_w_t_h_k<<<dim3(16, 16), 256, 0, stream>>>(K_w, kwT);
  cvt_f32_bf16_k<<<1024, 256, 0, stream>>>(V_w, vw, 1024L * 1024 / 4);
  // 4. q' = x @ K_w  (fp16 2-pass, 2 blocks/CU)
  gemm2_8ph_k<0><<<512, 512, 0, stream>>>(xhi, xlo, kwT, qhi, qlo);
  // 5. scores[b] = q'[b] @ hf16[b]^T
  gemm2_8ph_k<1><<<512, 512, 0, stream>>>(qhi, qlo, hf16, scoresF, nullptr);
  // 6. softmax over S -> compact bf16 attn
  softmax_k<<<16384, 256, 0, stream>>>(scoresF, attn);
  // 7. ctx[b] = attn[b] @ hT[b]^T
  gemm1_8ph_k<0><<<256, 512, 0, stream>>>(attn, hT, nullptr, ctx);
  // 8. out = sigmoid(ctx @ V_w^T + V_b)
  gemm1_8ph_k<1><<<256, 512, 0, stream>>>(ctx, vw, V_b, out);
}

// Round 13
// 322.435 us; speedup vs baseline: 1.0426x; 1.0426x over previous
//
#include <hip/hip_runtime.h>

typedef unsigned short u16;
typedef __attribute__((ext_vector_type(8))) short short8;
typedef __attribute__((ext_vector_type(8))) _Float16 half8;
typedef __attribute__((ext_vector_type(4))) float f32x4;
typedef __attribute__((ext_vector_type(4))) u16 u16x4;
typedef __attribute__((ext_vector_type(4))) unsigned int u32x4;

#define DEVINL static __device__ __forceinline__

DEVINL u16 f2bf(float f) {
  unsigned u = __builtin_bit_cast(unsigned, f);
  u += 0x7fffu + ((u >> 16) & 1u);
  return (u16)(u >> 16);
}
DEVINL float bf2f(u16 h) {
  return __builtin_bit_cast(float, ((unsigned)h) << 16);
}
DEVINL u16 f2h(float f) { return __builtin_bit_cast(u16, (_Float16)f); }
DEVINL float h2f(u16 h) { return (float)__builtin_bit_cast(_Float16, h); }

// async global->LDS, 16B per lane; lds base must be wave-uniform
DEVINL void gload16(const void* g, void* l) {
  __builtin_amdgcn_global_load_lds(
      (const __attribute__((address_space(1))) void*)g,
      (__attribute__((address_space(3))) void*)l, 16, 0, 0);
}

#define BAR() asm volatile("s_barrier" ::: "memory")
#define WAIT_VMN(n) asm volatile("s_waitcnt vmcnt(" #n ")" ::: "memory")
#define WAIT_VM_LGKM0() asm volatile("s_waitcnt vmcnt(0) lgkmcnt(0)" ::: "memory")

// ---------------- converts ----------------

// hidden [S=1024,B=32,H=1024] f32 -> hf16 [B,S,H] fp16 + hT [B,H,S] bf16
__global__ __launch_bounds__(256) void cvt_hidden2_k(const float* __restrict__ hid,
                                                     u16* __restrict__ hf,
                                                     u16* __restrict__ hT) {
  __shared__ u16 tl[64][72];
  const int s0 = blockIdx.x * 64;
  const int h0 = blockIdx.y * 64;
  const int b = blockIdx.z;
  const int t = threadIdx.x;
  const int r = t >> 4;
  const int c4 = (t & 15) * 4;
#pragma unroll
  for (int it = 0; it < 4; ++it) {
    const int s = it * 16 + r;
    const f32x4 v = *(const f32x4*)(hid + ((size_t)(s0 + s) * 32 + b) * 1024 + h0 + c4);
    u16x4 of;
    const int cs = c4 ^ (it << 2);  // (s>>4)==it here
#pragma unroll
    for (int j = 0; j < 4; ++j) {
      of[j] = f2h(v[j]);
      tl[s][cs + j] = f2bf(v[j]);
    }
    *(u16x4*)(hf + ((size_t)b * 1024 + s0 + s) * 1024 + h0 + c4) = of;
  }
  __syncthreads();
  const int h = t >> 2;
  const int sq = (t & 3) * 16;
  u16 tmp[16] __attribute__((aligned(16)));
#pragma unroll
  for (int i = 0; i < 16; ++i)
    tmp[i] = tl[sq + i][h ^ ((((sq + i) >> 4) & 3) << 2)];
  u16* dst = hT + ((size_t)b * 1024 + h0 + h) * 1024 + s0 + sq;
  *(u32x4*)(dst) = *(const u32x4*)&tmp[0];
  *(u32x4*)(dst + 8) = *(const u32x4*)&tmp[8];
}

// generic f32 -> bf16 (single)
__global__ __launch_bounds__(256) void cvt_f32_bf16_k(const float* __restrict__ in,
                                                      u16* __restrict__ out, long n4) {
  long i = (long)blockIdx.x * 256 + threadIdx.x;
  const long stride = (long)gridDim.x * 256;
  for (; i < n4; i += stride) {
    const f32x4 v = ((const f32x4*)in)[i];
    u16x4 o;
#pragma unroll
    for (int j = 0; j < 4; ++j) o[j] = f2bf(v[j]);
    ((u16x4*)out)[i] = o;
  }
}

// K_w [j=1024][h=1024] f32 -> transposed single fp16: out[h][j]
__global__ __launch_bounds__(256) void cvt_w_t_h_k(const float* __restrict__ in,
                                                   u16* __restrict__ out) {
  __shared__ float tile[64][65];
  const int bh = blockIdx.x * 64;
  const int bj = blockIdx.y * 64;
  const int t = threadIdx.x;
  const int r = t >> 4;
  const int c4 = (t & 15) * 4;
#pragma unroll
  for (int it = 0; it < 4; ++it) {
    const int row = it * 16 + r;
    const f32x4 v = *(const f32x4*)(in + (size_t)(bj + row) * 1024 + bh + c4);
#pragma unroll
    for (int j = 0; j < 4; ++j) tile[c4 + j][row] = v[j];
  }
  __syncthreads();
#pragma unroll
  for (int it = 0; it < 4; ++it) {
    const int hrow = it * 16 + r;
    u16x4 of;
#pragma unroll
    for (int j = 0; j < 4; ++j) of[j] = f2h(tile[hrow][c4 + j]);
    *(u16x4*)(out + (size_t)(bh + hrow) * 1024 + bj + c4) = of;
  }
}

// ---------------- qp: fused-convert 2-pass fp16 GEMM ----------------
// q' = x @ kwT^T with x read as f32 and split to fp16 hi/lo IN-KERNEL
// (register convert + swizzled ds_write — replaces cvt_split_h + gload_lds).
// 256x256 tile, BK=32, 8 waves (2x4), wave tile 128x64, 2-buf (96 KB LDS).
// A-pair LDS rows 128B: row r chunk c holds global chunk g=c^(r&7); g<4 hi, g>=4 lo.
// B single fp16 (rows 64B, chunk g = c ^ ((r>>1)&3)), staged via gload_lds.
// Boundary: vmcnt(0)+lgkmcnt(0) (ds_write visibility) + s_barrier, once per K-tile.
__global__ __launch_bounds__(512) void gemm_qp_k(
    const float* __restrict__ X, const u16* __restrict__ Bm,
    u16* __restrict__ Chi, u16* __restrict__ Clo) {
  __shared__ u16 lA[2][256 * 64];  // 64 KiB
  __shared__ u16 lB[2][256 * 32];  // 32 KiB
  const int bid = blockIdx.x;
  const int swz = (bid & 7) * 32 + (bid >> 3);  // bijective on 256; XCD-chunked
  const int m0 = (swz >> 2) * 256;
  const int n0 = (swz & 3) * 256;
  const int tid = threadIdx.x;
  const int lane = tid & 63, wid = tid >> 6;
  const int wr = wid >> 2, wc = wid & 3;
  const int fr = lane & 15, fk = lane >> 4;

  f32x4 acc[8][4] = {};

  // A fused stage: 1024 (hi,lo) slot-pairs, 2 per thread.
#define STAGEAF(pb, kt)                                                        \
  {                                                                            \
    _Pragma("unroll") for (int j = 0; j < 2; ++j) {                            \
      const int ps = j * 512 + tid;                                            \
      const int r = ps >> 2, q = ps & 3;                                       \
      const float* src = X + (size_t)(m0 + r) * 1024 + (kt) * 32 + q * 8;      \
      const f32x4 v0 = *(const f32x4*)src;                                     \
      const f32x4 v1 = *(const f32x4*)(src + 4);                               \
      u16x4 h0, h1, l0, l1;                                                    \
      _Pragma("unroll") for (int e = 0; e < 4; ++e) {                          \
        h0[e] = f2h(v0[e]); l0[e] = f2h(v0[e] - h2f(h0[e]));                   \
        h1[e] = f2h(v1[e]); l1[e] = f2h(v1[e] - h2f(h1[e]));                   \
      }                                                                        \
      const int c = q ^ (r & 7);                                               \
      u16* dh = &lA[pb][r * 64 + c * 8];                                       \
      u16* dl = &lA[pb][r * 64 + (c ^ 4) * 8];                                 \
      *(u16x4*)dh = h0; *(u16x4*)(dh + 4) = h1;                                \
      *(u16x4*)dl = l0; *(u16x4*)(dl + 4) = l1;                                \
    }                                                                          \
  }
  // B K-tile: 2 gload_lds per wave
#define STAGEB(pb, kt)                                                         \
  {                                                                            \
    _Pragma("unroll") for (int j = 0; j < 2; ++j) {                            \
      const int slot = j * 512 + tid;                                          \
      const int r = slot >> 2;                                                 \
      const int g = (slot & 3) ^ ((r >> 1) & 3);                               \
      gload16(Bm + (size_t)(n0 + r) * 1024 + (kt) * 32 + g * 8,                \
              &lB[pb][(j * 512 + wid * 64) * 8]);                              \
    }                                                                          \
  }

  STAGEAF(0, 0);
  STAGEB(0, 0);

  for (int t = 0; t < 32; ++t) {
    const int p = t & 1;
    WAIT_VM_LGKM0();
    BAR();
    half8 bf[4];
#pragma unroll
    for (int nf = 0; nf < 4; ++nf) {
      const int rn = wc * 64 + nf * 16 + fr;
      const int cn = fk ^ ((rn >> 1) & 3);
      bf[nf] = *(const half8*)&lB[p][rn * 32 + cn * 8];
    }
    if (t < 31) {
      STAGEB(p ^ 1, t + 1);
      STAGEAF(p ^ 1, t + 1);
    }
#pragma unroll
    for (int ph = 0; ph < 4; ++ph) {
      half8 ah[2], al[2];
#pragma unroll
      for (int i = 0; i < 2; ++i) {
        const int r = wr * 128 + (ph * 2 + i) * 16 + fr;
        const int ch = fk ^ (r & 7);
        ah[i] = *(const half8*)&lA[p][r * 64 + ch * 8];
        al[i] = *(const half8*)&lA[p][r * 64 + (ch ^ 4) * 8];
      }
      __builtin_amdgcn_s_setprio(1);
#pragma unroll
      for (int i = 0; i < 2; ++i)
#pragma unroll
        for (int nf = 0; nf < 4; ++nf) {
          acc[ph * 2 + i][nf] =
              __builtin_amdgcn_mfma_f32_16x16x32_f16(ah[i], bf[nf], acc[ph * 2 + i][nf], 0, 0, 0);
          acc[ph * 2 + i][nf] =
              __builtin_amdgcn_mfma_f32_16x16x32_f16(al[i], bf[nf], acc[ph * 2 + i][nf], 0, 0, 0);
        }
      __builtin_amdgcn_s_setprio(0);
    }
  }
#undef STAGEAF
#undef STAGEB

  const int cb = n0 + wc * 64 + fr;
  const int rb = m0 + wr * 128 + fk * 4;
#pragma unroll
  for (int mf = 0; mf < 8; ++mf)
#pragma unroll
    for (int nf = 0; nf < 4; ++nf) {
      const int col = cb + nf * 16;
#pragma unroll
      for (int j = 0; j < 4; ++j) {
        const int row = rb + mf * 16 + j;
        const float kv = acc[mf][nf][j];
        const u16 hi = f2h(kv);
        Chi[(size_t)row * 1024 + col] = hi;
        Clo[(size_t)row * 1024 + col] = f2h(kv - h2f(hi));
      }
    }
}

// ---------------- scores: 2-pass fp16 GEMM, 3-deep, counted vmcnt (r11 best) ----------------
// scores[b] = (Qh+Ql)[b] @ Hf[b]^T, batched B=32, f32 out.
__global__ __launch_bounds__(512) void gemm_sc_k(
    const u16* __restrict__ Qh_, const u16* __restrict__ Ql_,
    const u16* __restrict__ Hf_, float* __restrict__ S) {
  __shared__ u16 lA[3][256 * 64];  // 96 KiB
  __shared__ u16 lB[3][256 * 32];  // 48 KiB
  const int bid = blockIdx.x;
  const int swz = (bid & 7) * 32 + (bid >> 3);
  const int z = swz >> 3;
  const int m0 = ((swz >> 2) & 1) * 256;
  const int n0 = (swz & 3) * 256;
  const u16* Ah = Qh_ + (size_t)z * 512 * 1024;
  const u16* Al = Ql_ + (size_t)z * 512 * 1024;
  const u16* Bm = Hf_ + (size_t)z * 1024 * 1024;
  float* Cf = S + (size_t)z * 512 * 1024;
  const int tid = threadIdx.x;
  const int lane = tid & 63, wid = tid >> 6;
  const int wr = wid >> 2, wc = wid & 3;
  const int fr = lane & 15, fk = lane >> 4;

  f32x4 acc[8][4] = {};

#define STAGEA(pb, kt)                                                         \
  {                                                                            \
    _Pragma("unroll") for (int j = 0; j < 4; ++j) {                            \
      const int slot = j * 512 + tid;                                          \
      const int r = slot >> 3;                                                 \
      const int g = (slot & 7) ^ (r & 7);                                      \
      const u16* src = (g < 4) ? Ah : Al;                                      \
      gload16(src + (size_t)(m0 + r) * 1024 + (kt) * 32 + (g & 3) * 8,         \
              &lA[pb][(j * 512 + wid * 64) * 8]);                              \
    }                                                                          \
  }
#define STAGEB(pb, kt)                                                         \
  {                                                                            \
    _Pragma("unroll") for (int j = 0; j < 2; ++j) {                            \
      const int slot = j * 512 + tid;                                          \
      const int r = slot >> 2;                                                 \
      const int g = (slot & 3) ^ ((r >> 1) & 3);                               \
      gload16(Bm + (size_t)(n0 + r) * 1024 + (kt) * 32 + g * 8,                \
              &lB[pb][(j * 512 + wid * 64) * 8]);                              \
    }                                                                          \
  }

  STAGEA(0, 0);
  STAGEB(0, 0);
  STAGEA(1, 1);
  STAGEB(1, 1);

  int cur = 0;
  for (int t = 0; t < 32; ++t) {
    if (t < 31) {
      WAIT_VMN(6);
    } else {
      WAIT_VMN(0);
    }
    BAR();
    int pre = cur + 2;
    if (pre >= 3) pre -= 3;
    half8 bf[4];
#pragma unroll
    for (int nf = 0; nf < 4; ++nf) {
      const int rn = wc * 64 + nf * 16 + fr;
      const int cn = fk ^ ((rn >> 1) & 3);
      bf[nf] = *(const half8*)&lB[cur][rn * 32 + cn * 8];
    }
    if (t < 30) {
      STAGEA(pre, t + 2);
      STAGEB(pre, t + 2);
    }
#pragma unroll
    for (int ph = 0; ph < 4; ++ph) {
      half8 ah[2], al[2];
#pragma unroll
      for (int i = 0; i < 2; ++i) {
        const int r = wr * 128 + (ph * 2 + i) * 16 + fr;
        const int ch = fk ^ (r & 7);
        ah[i] = *(const half8*)&lA[cur][r * 64 + ch * 8];
        al[i] = *(const half8*)&lA[cur][r * 64 + (ch ^ 4) * 8];
      }
      __builtin_amdgcn_s_setprio(1);
#pragma unroll
      for (int i = 0; i < 2; ++i)
#pragma unroll
        for (int nf = 0; nf < 4; ++nf) {
          acc[ph * 2 + i][nf] =
              __builtin_amdgcn_mfma_f32_16x16x32_f16(ah[i], bf[nf], acc[ph * 2 + i][nf], 0, 0, 0);
          acc[ph * 2 + i][nf] =
              __builtin_amdgcn_mfma_f32_16x16x32_f16(al[i], bf[nf], acc[ph * 2 + i][nf], 0, 0, 0);
        }
      __builtin_amdgcn_s_setprio(0);
    }
    ++cur;
    if (cur == 3) cur = 0;
  }
#undef STAGEA
#undef STAGEB

  const int cb = n0 + wc * 64 + fr;
  const int rb = m0 + wr * 128 + fk * 4;
#pragma unroll
  for (int mf = 0; mf < 8; ++mf)
#pragma unroll
    for (int nf = 0; nf < 4; ++nf) {
      const int col = cb + nf * 16;
#pragma unroll
      for (int j = 0; j < 4; ++j) {
        const int row = rb + mf * 16 + j;
        Cf[(size_t)row * 1024 + col] = acc[mf][nf][j];
      }
    }
}

// ---------------- single-pass bf16 GEMM, 2-buf, 1 barrier per K-tile ----------------
// CM 0: ctx = attn[b] @ hT[b]^T, batched, bf16 out.
// CM 1: out = sigmoid(A @ Bt^T + bias), flat M=16384, f32 out.
template <int CM>
__global__ __launch_bounds__(512) void gemm1_8ph_k(
    const u16* __restrict__ A_, const u16* __restrict__ Bt_,
    const float* __restrict__ bias, void* __restrict__ Cout) {
  __shared__ u16 lds[2][2][256 * 64];  // 131072 B
  const int bid = blockIdx.x;
  const int swz = (bid & 7) * 32 + (bid >> 3);
  int m0, n0;
  const u16 *A, *Bt;
  float* Cf = nullptr;
  u16* Cb = nullptr;
  if (CM == 0) {
    const int z = swz >> 3;
    m0 = ((swz >> 2) & 1) * 256;
    n0 = (swz & 3) * 256;
    A = A_ + (size_t)z * 512 * 1024;
    Bt = Bt_ + (size_t)z * 1024 * 1024;
    Cb = (u16*)Cout + (size_t)z * 512 * 1024;
  } else {
    m0 = (swz >> 2) * 256;
    n0 = (swz & 3) * 256;
    A = A_; Bt = Bt_;
    Cf = (float*)Cout;
  }
  const int tid = threadIdx.x;
  const int lane = tid & 63, wid = tid >> 6;
  const int wr = wid >> 2, wc = wid & 3;
  const int fr = lane & 15, fk = lane >> 4;

  f32x4 acc[8][4] = {};

#define STAGE1(pb, q, gp, rb, kt)                                              \
  {                                                                            \
    _Pragma("unroll") for (int j = 0; j < 4; ++j) {                            \
      const int slot = j * 512 + tid;                                          \
      const int r = slot >> 3;                                                 \
      const int g = (slot & 7) ^ (r & 7);                                      \
      gload16((gp) + (size_t)((rb) + r) * 1024 + (kt) * 64 + g * 8,            \
              &lds[pb][q][(j * 512 + wid * 64) * 8]);                          \
    }                                                                          \
  }

  STAGE1(0, 0, A, m0, 0);
  STAGE1(0, 1, Bt, n0, 0);

  for (int t = 0; t < 16; ++t) {
    const int p = t & 1;
    WAIT_VMN(0);
    BAR();
    short8 bfr[4][2];
#pragma unroll
    for (int nf = 0; nf < 4; ++nf) {
      const int rn = wc * 64 + nf * 16 + fr;
#pragma unroll
      for (int ks = 0; ks < 2; ++ks) {
        const int g = (ks * 4 + fk) ^ (rn & 7);
        bfr[nf][ks] = *(const short8*)&lds[p][1][rn * 64 + g * 8];
      }
    }
    if (t < 15) {
      STAGE1(p ^ 1, 0, A, m0, t + 1);
      STAGE1(p ^ 1, 1, Bt, n0, t + 1);
    }
#pragma unroll
    for (int ph = 0; ph < 4; ++ph) {
      short8 a[2][2];
#pragma unroll
      for (int i = 0; i < 2; ++i) {
        const int r = wr * 128 + (ph * 2 + i) * 16 + fr;
#pragma unroll
        for (int ks = 0; ks < 2; ++ks) {
          const int g = (ks * 4 + fk) ^ (r & 7);
          a[i][ks] = *(const short8*)&lds[p][0][r * 64 + g * 8];
        }
      }
      __builtin_amdgcn_s_setprio(1);
#pragma unroll
      for (int i = 0; i < 2; ++i)
#pragma unroll
        for (int nf = 0; nf < 4; ++nf) {
          acc[ph * 2 + i][nf] = __builtin_amdgcn_mfma_f32_16x16x32_bf16(
              a[i][0], bfr[nf][0], acc[ph * 2 + i][nf], 0, 0, 0);
          acc[ph * 2 + i][nf] = __builtin_amdgcn_mfma_f32_16x16x32_bf16(
              a[i][1], bfr[nf][1], acc[ph * 2 + i][nf], 0, 0, 0);
        }
      __builtin_amdgcn_s_setprio(0);
    }
  }
#undef STAGE1

  const int cb = n0 + wc * 64 + fr;
  const int rb = m0 + wr * 128 + fk * 4;
  if (CM == 0) {
#pragma unroll
    for (int mf = 0; mf < 8; ++mf)
#pragma unroll
      for (int nf = 0; nf < 4; ++nf) {
        const int col = cb + nf * 16;
#pragma unroll
        for (int j = 0; j < 4; ++j) {
          const int row = rb + mf * 16 + j;
          Cb[(size_t)row * 1024 + col] = f2bf(acc[mf][nf][j]);
        }
      }
  } else {
#pragma unroll
    for (int mf = 0; mf < 8; ++mf)
#pragma unroll
      for (int nf = 0; nf < 4; ++nf) {
        const int col = cb + nf * 16;
        const float bv = bias[col];
#pragma unroll
        for (int j = 0; j < 4; ++j) {
          const int row = rb + mf * 16 + j;
          const float xv = acc[mf][nf][j] + bv;
          Cf[(size_t)row * 1024 + col] = 1.0f / (1.0f + __expf(-xv));
        }
      }
  }
}

// ---------------- softmax over last dim (1024), writes compact bf16 attn ----------------
__global__ __launch_bounds__(256) void softmax_k(const float* __restrict__ S,
                                                 u16* __restrict__ Attn) {
  const float* rp = S + (size_t)blockIdx.x * 1024;
  const int tid = threadIdx.x;
  const int lane = tid & 63, wid = tid >> 6;
  const f32x4 v = ((const f32x4*)rp)[tid];
  float mx = fmaxf(fmaxf(v[0], v[1]), fmaxf(v[2], v[3]));
#pragma unroll
  for (int off = 32; off; off >>= 1) mx = fmaxf(mx, __shfl_xor(mx, off));
  __shared__ float red[4];
  __shared__ float red2[4];
  if (lane == 0) red[wid] = mx;
  __syncthreads();
  mx = fmaxf(fmaxf(red[0], red[1]), fmaxf(red[2], red[3]));
  const float e0 = __expf(v[0] - mx), e1 = __expf(v[1] - mx);
  const float e2 = __expf(v[2] - mx), e3 = __expf(v[3] - mx);
  float s = (e0 + e1) + (e2 + e3);
#pragma unroll
  for (int off = 32; off; off >>= 1) s += __shfl_xor(s, off);
  if (lane == 0) red2[wid] = s;
  __syncthreads();
  const float inv = 1.0f / (red2[0] + red2[1] + red2[2] + red2[3]);
  u16x4 o;
  o[0] = f2bf(e0 * inv); o[1] = f2bf(e1 * inv); o[2] = f2bf(e2 * inv); o[3] = f2bf(e3 * inv);
  ((u16x4*)(Attn + (size_t)blockIdx.x * 1024))[tid] = o;
}

// ---------------- launch ----------------
// Shapes: S=1024, B=32, H=1024, T=512.
//   q'  = x @ K_w            (fused f32->fp16-split convert + 2-pass fp16 GEMM; K_b dropped)
//   scr = q'[b] @ hf16[b]^T  (fp16 2-pass, 3-buf counted-vmcnt — r11 best)
//   attn = softmax(scr)      (compact bf16)
//   ctx = attn[b] @ hT[b]^T  (bf16, 2-buf, 1-barrier/K-tile)
//   out = sigmoid(ctx @ V_w^T + V_b)
// ws (MB): hf16 0-64 (attn reuses 0-32) | hT 64-128 | qhi 128-160 (ctx reuses) |
//          qlo 160-192 | scores f32 192-256 | kwT 256-258 | vw 258-260
extern "C" void kernel_launch(void* const* d_in, const int* in_sizes, int n_in,
                              void* d_out, int out_size, void* d_ws, size_t ws_size,
                              hipStream_t stream) {
  const float* hidden = (const float*)d_in[0];
  const float* x = (const float*)d_in[1];
  // d_in[2] problem_q unused; d_in[4] K_b dropped (softmax shift invariance)
  const float* K_w = (const float*)d_in[3];
  const float* V_w = (const float*)d_in[5];
  const float* V_b = (const float*)d_in[6];

  char* ws = (char*)d_ws;
  u16* hf16 = (u16*)(ws);
  u16* hT = (u16*)(ws + 67108864);
  u16* qhi = (u16*)(ws + 134217728);
  u16* qlo = (u16*)(ws + 167772160);
  float* scoresF = (float*)(ws + 201326592);
  u16* attn = hf16;  // reuse (hf16 dead after scores)
  u16* ctx = qhi;    // reuse (q' dead after scores)
  u16* kwT = (u16*)(ws + 268435456);
  u16* vw = kwT + 1024 * 1024;
  float* out = (float*)d_out;

  // 1. hidden [S,B,H] -> fp16 [B,S,H] + transposed bf16 [B,H,S]
  cvt_hidden2_k<<<dim3(16, 16, 32), 256, 0, stream>>>(hidden, hf16, hT);
  // 2. weights: K_w transposed fp16, V_w bf16
  cvt_w_t_h_k<<<dim3(16, 16), 256, 0, stream>>>(K_w, kwT);
  cvt_f32_bf16_k<<<1024, 256, 0, stream>>>(V_w, vw, 1024L * 1024 / 4);
  // 3. q' = x @ K_w  (x f32 consumed directly; split done in-kernel)
  gemm_qp_k<<<256, 512, 0, stream>>>(x, kwT, qhi, qlo);
  // 4. scores[b] = q'[b] @ hf16[b]^T
  gemm_sc_k<<<256, 512, 0, stream>>>(qhi, qlo, hf16, scoresF);
  // 5. softmax over S -> compact bf16 attn
  softmax_k<<<16384, 256, 0, stream>>>(scoresF, attn);
  // 6. ctx[b] = attn[b] @ hT[b]^T
  gemm1_8ph_k<0><<<256, 512, 0, stream>>>(attn, hT, nullptr, ctx);
  // 7. out = sigmoid(ctx @ V_w^T + V_b)
  gemm1_8ph_k<1><<<256, 512, 0, stream>>>(ctx, vw, V_b, out);
}

// Round 14
// 321.503 us; speedup vs baseline: 1.0457x; 1.0029x over previous
//
#include <hip/hip_runtime.h>

typedef unsigned short u16;
typedef __attribute__((ext_vector_type(8))) short short8;
typedef __attribute__((ext_vector_type(8))) _Float16 half8;
typedef __attribute__((ext_vector_type(4))) float f32x4;
typedef __attribute__((ext_vector_type(4))) u16 u16x4;
typedef __attribute__((ext_vector_type(4))) unsigned int u32x4;

#define DEVINL static __device__ __forceinline__

DEVINL u16 f2bf(float f) {
  unsigned u = __builtin_bit_cast(unsigned, f);
  u += 0x7fffu + ((u >> 16) & 1u);
  return (u16)(u >> 16);
}
DEVINL float bf2f(u16 h) {
  return __builtin_bit_cast(float, ((unsigned)h) << 16);
}
DEVINL u16 f2h(float f) { return __builtin_bit_cast(u16, (_Float16)f); }
DEVINL float h2f(u16 h) { return (float)__builtin_bit_cast(_Float16, h); }

// async global->LDS, 16B per lane; lds base must be wave-uniform
DEVINL void gload16(const void* g, void* l) {
  __builtin_amdgcn_global_load_lds(
      (const __attribute__((address_space(1))) void*)g,
      (__attribute__((address_space(3))) void*)l, 16, 0, 0);
}

#define BAR() asm volatile("s_barrier" ::: "memory")
#define WAIT_VMN(n) asm volatile("s_waitcnt vmcnt(" #n ")" ::: "memory")
#define WAIT_VM_LGKM0() asm volatile("s_waitcnt vmcnt(0) lgkmcnt(0)" ::: "memory")

// ---------------- converts ----------------

// hidden [S=1024,B=32,H=1024] f32 -> hf16 [B,S,H] fp16 + hT [B,H,S] bf16
// 512 threads, 64s x 128h tile: 512B coalesced reads, 256B hf writes, 128B hT rows.
// LDS transpose with XOR col-swizzle (col ^= ((s>>4)&3)<<2).
__global__ __launch_bounds__(512) void cvt_hidden2_k(const float* __restrict__ hid,
                                                     u16* __restrict__ hf,
                                                     u16* __restrict__ hT) {
  __shared__ u16 tl[64][136];  // pad 8 u16
  const int s0 = blockIdx.x * 64;
  const int h0 = blockIdx.y * 128;
  const int b = blockIdx.z;
  const int t = threadIdx.x;
  const int r = t >> 5;          // 0..15
  const int c4 = (t & 31) * 4;   // 0..124
#pragma unroll
  for (int it = 0; it < 4; ++it) {
    const int s = it * 16 + r;
    const f32x4 v = *(const f32x4*)(hid + ((size_t)(s0 + s) * 32 + b) * 1024 + h0 + c4);
    u16x4 of;
    const int cs = c4 ^ (it << 2);  // (s>>4)==it here
#pragma unroll
    for (int j = 0; j < 4; ++j) {
      of[j] = f2h(v[j]);
      tl[s][cs + j] = f2bf(v[j]);
    }
    *(u16x4*)(hf + ((size_t)b * 1024 + s0 + s) * 1024 + h0 + c4) = of;
  }
  __syncthreads();
  const int h = t >> 2;          // 0..127
  const int sq = (t & 3) * 16;
  u16 tmp[16] __attribute__((aligned(16)));
#pragma unroll
  for (int i = 0; i < 16; ++i)
    tmp[i] = tl[sq + i][h ^ ((((sq + i) >> 4) & 3) << 2)];
  u16* dst = hT + ((size_t)b * 1024 + h0 + h) * 1024 + s0 + sq;
  *(u32x4*)(dst) = *(const u32x4*)&tmp[0];
  *(u32x4*)(dst + 8) = *(const u32x4*)&tmp[8];
}

// generic f32 -> bf16 (single)
__global__ __launch_bounds__(256) void cvt_f32_bf16_k(const float* __restrict__ in,
                                                      u16* __restrict__ out, long n4) {
  long i = (long)blockIdx.x * 256 + threadIdx.x;
  const long stride = (long)gridDim.x * 256;
  for (; i < n4; i += stride) {
    const f32x4 v = ((const f32x4*)in)[i];
    u16x4 o;
#pragma unroll
    for (int j = 0; j < 4; ++j) o[j] = f2bf(v[j]);
    ((u16x4*)out)[i] = o;
  }
}

// K_w [j=1024][h=1024] f32 -> transposed single fp16: out[h][j]
__global__ __launch_bounds__(256) void cvt_w_t_h_k(const float* __restrict__ in,
                                                   u16* __restrict__ out) {
  __shared__ float tile[64][65];
  const int bh = blockIdx.x * 64;
  const int bj = blockIdx.y * 64;
  const int t = threadIdx.x;
  const int r = t >> 4;
  const int c4 = (t & 15) * 4;
#pragma unroll
  for (int it = 0; it < 4; ++it) {
    const int row = it * 16 + r;
    const f32x4 v = *(const f32x4*)(in + (size_t)(bj + row) * 1024 + bh + c4);
#pragma unroll
    for (int j = 0; j < 4; ++j) tile[c4 + j][row] = v[j];
  }
  __syncthreads();
#pragma unroll
  for (int it = 0; it < 4; ++it) {
    const int hrow = it * 16 + r;
    u16x4 of;
#pragma unroll
    for (int j = 0; j < 4; ++j) of[j] = f2h(tile[hrow][c4 + j]);
    *(u16x4*)(out + (size_t)(bh + hrow) * 1024 + bj + c4) = of;
  }
}

// ---------------- qp: fused-convert 2-pass fp16 GEMM ----------------
// q' = x @ kwT^T with x read as f32 and split to fp16 hi/lo IN-KERNEL.
// A-stage now emits single ds_write_b128 per (hi|lo): chunk c spans 8 values
// x 16B -> all 32 banks at the 8-dword/bank floor (conflict-free).
__global__ __launch_bounds__(512) void gemm_qp_k(
    const float* __restrict__ X, const u16* __restrict__ Bm,
    u16* __restrict__ Chi, u16* __restrict__ Clo) {
  __shared__ u16 lA[2][256 * 64];  // 64 KiB
  __shared__ u16 lB[2][256 * 32];  // 32 KiB
  const int bid = blockIdx.x;
  const int swz = (bid & 7) * 32 + (bid >> 3);  // bijective on 256; XCD-chunked
  const int m0 = (swz >> 2) * 256;
  const int n0 = (swz & 3) * 256;
  const int tid = threadIdx.x;
  const int lane = tid & 63, wid = tid >> 6;
  const int wr = wid >> 2, wc = wid & 3;
  const int fr = lane & 15, fk = lane >> 4;

  f32x4 acc[8][4] = {};

  // A fused stage: 1024 (hi,lo) slot-pairs, 2 per thread; b128 stores.
#define STAGEAF(pb, kt)                                                        \
  {                                                                            \
    _Pragma("unroll") for (int j = 0; j < 2; ++j) {                            \
      const int ps = j * 512 + tid;                                            \
      const int r = ps >> 2, q = ps & 3;                                       \
      const float* src = X + (size_t)(m0 + r) * 1024 + (kt) * 32 + q * 8;      \
      const f32x4 v0 = *(const f32x4*)src;                                     \
      const f32x4 v1 = *(const f32x4*)(src + 4);                               \
      short8 hs, ls;                                                           \
      _Pragma("unroll") for (int e = 0; e < 4; ++e) {                          \
        const u16 a0 = f2h(v0[e]);                                             \
        const u16 a1 = f2h(v1[e]);                                             \
        hs[e] = (short)a0;                                                     \
        hs[e + 4] = (short)a1;                                                 \
        ls[e] = (short)f2h(v0[e] - h2f(a0));                                   \
        ls[e + 4] = (short)f2h(v1[e] - h2f(a1));                               \
      }                                                                        \
      const int c = q ^ (r & 7);                                               \
      *(short8*)&lA[pb][r * 64 + c * 8] = hs;                                  \
      *(short8*)&lA[pb][r * 64 + (c ^ 4) * 8] = ls;                            \
    }                                                                          \
  }
  // B K-tile: 2 gload_lds per wave
#define STAGEB(pb, kt)                                                         \
  {                                                                            \
    _Pragma("unroll") for (int j = 0; j < 2; ++j) {                            \
      const int slot = j * 512 + tid;                                          \
      const int r = slot >> 2;                                                 \
      const int g = (slot & 3) ^ ((r >> 1) & 3);                               \
      gload16(Bm + (size_t)(n0 + r) * 1024 + (kt) * 32 + g * 8,                \
              &lB[pb][(j * 512 + wid * 64) * 8]);                              \
    }                                                                          \
  }

  STAGEAF(0, 0);
  STAGEB(0, 0);

  for (int t = 0; t < 32; ++t) {
    const int p = t & 1;
    WAIT_VM_LGKM0();
    BAR();
    half8 bf[4];
#pragma unroll
    for (int nf = 0; nf < 4; ++nf) {
      const int rn = wc * 64 + nf * 16 + fr;
      const int cn = fk ^ ((rn >> 1) & 3);
      bf[nf] = *(const half8*)&lB[p][rn * 32 + cn * 8];
    }
    if (t < 31) {
      STAGEB(p ^ 1, t + 1);
      STAGEAF(p ^ 1, t + 1);
    }
#pragma unroll
    for (int ph = 0; ph < 4; ++ph) {
      half8 ah[2], al[2];
#pragma unroll
      for (int i = 0; i < 2; ++i) {
        const int r = wr * 128 + (ph * 2 + i) * 16 + fr;
        const int ch = fk ^ (r & 7);
        ah[i] = *(const half8*)&lA[p][r * 64 + ch * 8];
        al[i] = *(const half8*)&lA[p][r * 64 + (ch ^ 4) * 8];
      }
      __builtin_amdgcn_s_setprio(1);
#pragma unroll
      for (int i = 0; i < 2; ++i)
#pragma unroll
        for (int nf = 0; nf < 4; ++nf) {
          acc[ph * 2 + i][nf] =
              __builtin_amdgcn_mfma_f32_16x16x32_f16(ah[i], bf[nf], acc[ph * 2 + i][nf], 0, 0, 0);
          acc[ph * 2 + i][nf] =
              __builtin_amdgcn_mfma_f32_16x16x32_f16(al[i], bf[nf], acc[ph * 2 + i][nf], 0, 0, 0);
        }
      __builtin_amdgcn_s_setprio(0);
    }
  }
#undef STAGEAF
#undef STAGEB

  const int cb = n0 + wc * 64 + fr;
  const int rb = m0 + wr * 128 + fk * 4;
#pragma unroll
  for (int mf = 0; mf < 8; ++mf)
#pragma unroll
    for (int nf = 0; nf < 4; ++nf) {
      const int col = cb + nf * 16;
#pragma unroll
      for (int j = 0; j < 4; ++j) {
        const int row = rb + mf * 16 + j;
        const float kv = acc[mf][nf][j];
        const u16 hi = f2h(kv);
        Chi[(size_t)row * 1024 + col] = hi;
        Clo[(size_t)row * 1024 + col] = f2h(kv - h2f(hi));
      }
    }
}

// ---------------- scores: 2-pass fp16 GEMM, 3-deep, counted vmcnt ----------------
// scores[b] = (Qh+Ql)[b] @ Hf[b]^T, batched B=32, f32 out.
__global__ __launch_bounds__(512) void gemm_sc_k(
    const u16* __restrict__ Qh_, const u16* __restrict__ Ql_,
    const u16* __restrict__ Hf_, float* __restrict__ S) {
  __shared__ u16 lA[3][256 * 64];  // 96 KiB
  __shared__ u16 lB[3][256 * 32];  // 48 KiB
  const int bid = blockIdx.x;
  const int swz = (bid & 7) * 32 + (bid >> 3);
  const int z = swz >> 3;
  const int m0 = ((swz >> 2) & 1) * 256;
  const int n0 = (swz & 3) * 256;
  const u16* Ah = Qh_ + (size_t)z * 512 * 1024;
  const u16* Al = Ql_ + (size_t)z * 512 * 1024;
  const u16* Bm = Hf_ + (size_t)z * 1024 * 1024;
  float* Cf = S + (size_t)z * 512 * 1024;
  const int tid = threadIdx.x;
  const int lane = tid & 63, wid = tid >> 6;
  const int wr = wid >> 2, wc = wid & 3;
  const int fr = lane & 15, fk = lane >> 4;

  f32x4 acc[8][4] = {};

#define STAGEA(pb, kt)                                                         \
  {                                                                            \
    _Pragma("unroll") for (int j = 0; j < 4; ++j) {                            \
      const int slot = j * 512 + tid;                                          \
      const int r = slot >> 3;                                                 \
      const int g = (slot & 7) ^ (r & 7);                                      \
      const u16* src = (g < 4) ? Ah : Al;                                      \
      gload16(src + (size_t)(m0 + r) * 1024 + (kt) * 32 + (g & 3) * 8,         \
              &lA[pb][(j * 512 + wid * 64) * 8]);                              \
    }                                                                          \
  }
#define STAGEB(pb, kt)                                                         \
  {                                                                            \
    _Pragma("unroll") for (int j = 0; j < 2; ++j) {                            \
      const int slot = j * 512 + tid;                                          \
      const int r = slot >> 2;                                                 \
      const int g = (slot & 3) ^ ((r >> 1) & 3);                               \
      gload16(Bm + (size_t)(n0 + r) * 1024 + (kt) * 32 + g * 8,                \
              &lB[pb][(j * 512 + wid * 64) * 8]);                              \
    }                                                                          \
  }

  STAGEA(0, 0);
  STAGEB(0, 0);
  STAGEA(1, 1);
  STAGEB(1, 1);

  int cur = 0;
  for (int t = 0; t < 32; ++t) {
    if (t < 31) {
      WAIT_VMN(6);
    } else {
      WAIT_VMN(0);
    }
    BAR();
    int pre = cur + 2;
    if (pre >= 3) pre -= 3;
    half8 bf[4];
#pragma unroll
    for (int nf = 0; nf < 4; ++nf) {
      const int rn = wc * 64 + nf * 16 + fr;
      const int cn = fk ^ ((rn >> 1) & 3);
      bf[nf] = *(const half8*)&lB[cur][rn * 32 + cn * 8];
    }
    if (t < 30) {
      STAGEA(pre, t + 2);
      STAGEB(pre, t + 2);
    }
#pragma unroll
    for (int ph = 0; ph < 4; ++ph) {
      half8 ah[2], al[2];
#pragma unroll
      for (int i = 0; i < 2; ++i) {
        const int r = wr * 128 + (ph * 2 + i) * 16 + fr;
        const int ch = fk ^ (r & 7);
        ah[i] = *(const half8*)&lA[cur][r * 64 + ch * 8];
        al[i] = *(const half8*)&lA[cur][r * 64 + (ch ^ 4) * 8];
      }
      __builtin_amdgcn_s_setprio(1);
#pragma unroll
      for (int i = 0; i < 2; ++i)
#pragma unroll
        for (int nf = 0; nf < 4; ++nf) {
          acc[ph * 2 + i][nf] =
              __builtin_amdgcn_mfma_f32_16x16x32_f16(ah[i], bf[nf], acc[ph * 2 + i][nf], 0, 0, 0);
          acc[ph * 2 + i][nf] =
              __builtin_amdgcn_mfma_f32_16x16x32_f16(al[i], bf[nf], acc[ph * 2 + i][nf], 0, 0, 0);
        }
      __builtin_amdgcn_s_setprio(0);
    }
    ++cur;
    if (cur == 3) cur = 0;
  }
#undef STAGEA
#undef STAGEB

  const int cb = n0 + wc * 64 + fr;
  const int rb = m0 + wr * 128 + fk * 4;
#pragma unroll
  for (int mf = 0; mf < 8; ++mf)
#pragma unroll
    for (int nf = 0; nf < 4; ++nf) {
      const int col = cb + nf * 16;
#pragma unroll
      for (int j = 0; j < 4; ++j) {
        const int row = rb + mf * 16 + j;
        Cf[(size_t)row * 1024 + col] = acc[mf][nf][j];
      }
    }
}

// ---------------- single-pass bf16 GEMM, 2-buf, 1 barrier per K-tile ----------------
// CM 0: ctx = attn[b] @ hT[b]^T, batched, bf16 out.
// CM 1: out = sigmoid(A @ Bt^T + bias), flat M=16384, f32 out.
template <int CM>
__global__ __launch_bounds__(512) void gemm1_8ph_k(
    const u16* __restrict__ A_, const u16* __restrict__ Bt_,
    const float* __restrict__ bias, void* __restrict__ Cout) {
  __shared__ u16 lds[2][2][256 * 64];  // 131072 B
  const int bid = blockIdx.x;
  const int swz = (bid & 7) * 32 + (bid >> 3);
  int m0, n0;
  const u16 *A, *Bt;
  float* Cf = nullptr;
  u16* Cb = nullptr;
  if (CM == 0) {
    const int z = swz >> 3;
    m0 = ((swz >> 2) & 1) * 256;
    n0 = (swz & 3) * 256;
    A = A_ + (size_t)z * 512 * 1024;
    Bt = Bt_ + (size_t)z * 1024 * 1024;
    Cb = (u16*)Cout + (size_t)z * 512 * 1024;
  } else {
    m0 = (swz >> 2) * 256;
    n0 = (swz & 3) * 256;
    A = A_; Bt = Bt_;
    Cf = (float*)Cout;
  }
  const int tid = threadIdx.x;
  const int lane = tid & 63, wid = tid >> 6;
  const int wr = wid >> 2, wc = wid & 3;
  const int fr = lane & 15, fk = lane >> 4;

  f32x4 acc[8][4] = {};

#define STAGE1(pb, q, gp, rb, kt)                                              \
  {                                                                            \
    _Pragma("unroll") for (int j = 0; j < 4; ++j) {                            \
      const int slot = j * 512 + tid;                                          \
      const int r = slot >> 3;                                                 \
      const int g = (slot & 7) ^ (r & 7);                                      \
      gload16((gp) + (size_t)((rb) + r) * 1024 + (kt) * 64 + g * 8,            \
              &lds[pb][q][(j * 512 + wid * 64) * 8]);                          \
    }                                                                          \
  }

  STAGE1(0, 0, A, m0, 0);
  STAGE1(0, 1, Bt, n0, 0);

  for (int t = 0; t < 16; ++t) {
    const int p = t & 1;
    WAIT_VMN(0);
    BAR();
    short8 bfr[4][2];
#pragma unroll
    for (int nf = 0; nf < 4; ++nf) {
      const int rn = wc * 64 + nf * 16 + fr;
#pragma unroll
      for (int ks = 0; ks < 2; ++ks) {
        const int g = (ks * 4 + fk) ^ (rn & 7);
        bfr[nf][ks] = *(const short8*)&lds[p][1][rn * 64 + g * 8];
      }
    }
    if (t < 15) {
      STAGE1(p ^ 1, 0, A, m0, t + 1);
      STAGE1(p ^ 1, 1, Bt, n0, t + 1);
    }
#pragma unroll
    for (int ph = 0; ph < 4; ++ph) {
      short8 a[2][2];
#pragma unroll
      for (int i = 0; i < 2; ++i) {
        const int r = wr * 128 + (ph * 2 + i) * 16 + fr;
#pragma unroll
        for (int ks = 0; ks < 2; ++ks) {
          const int g = (ks * 4 + fk) ^ (r & 7);
          a[i][ks] = *(const short8*)&lds[p][0][r * 64 + g * 8];
        }
      }
      __builtin_amdgcn_s_setprio(1);
#pragma unroll
      for (int i = 0; i < 2; ++i)
#pragma unroll
        for (int nf = 0; nf < 4; ++nf) {
          acc[ph * 2 + i][nf] = __builtin_amdgcn_mfma_f32_16x16x32_bf16(
              a[i][0], bfr[nf][0], acc[ph * 2 + i][nf], 0, 0, 0);
          acc[ph * 2 + i][nf] = __builtin_amdgcn_mfma_f32_16x16x32_bf16(
              a[i][1], bfr[nf][1], acc[ph * 2 + i][nf], 0, 0, 0);
        }
      __builtin_amdgcn_s_setprio(0);
    }
  }
#undef STAGE1

  const int cb = n0 + wc * 64 + fr;
  const int rb = m0 + wr * 128 + fk * 4;
  if (CM == 0) {
#pragma unroll
    for (int mf = 0; mf < 8; ++mf)
#pragma unroll
      for (int nf = 0; nf < 4; ++nf) {
        const int col = cb + nf * 16;
#pragma unroll
        for (int j = 0; j < 4; ++j) {
          const int row = rb + mf * 16 + j;
          Cb[(size_t)row * 1024 + col] = f2bf(acc[mf][nf][j]);
        }
      }
  } else {
#pragma unroll
    for (int mf = 0; mf < 8; ++mf)
#pragma unroll
      for (int nf = 0; nf < 4; ++nf) {
        const int col = cb + nf * 16;
        const float bv = bias[col];
#pragma unroll
        for (int j = 0; j < 4; ++j) {
          const int row = rb + mf * 16 + j;
          const float xv = acc[mf][nf][j] + bv;
          Cf[(size_t)row * 1024 + col] = 1.0f / (1.0f + __expf(-xv));
        }
      }
  }
}

// ---------------- softmax over last dim (1024), writes compact bf16 attn ----------------
__global__ __launch_bounds__(256) void softmax_k(const float* __restrict__ S,
                                                 u16* __restrict__ Attn) {
  const float* rp = S + (size_t)blockIdx.x * 1024;
  const int tid = threadIdx.x;
  const int lane = tid & 63, wid = tid >> 6;
  const f32x4 v = ((const f32x4*)rp)[tid];
  float mx = fmaxf(fmaxf(v[0], v[1]), fmaxf(v[2], v[3]));
#pragma unroll
  for (int off = 32; off; off >>= 1) mx = fmaxf(mx, __shfl_xor(mx, off));
  __shared__ float red[4];
  __shared__ float red2[4];
  if (lane == 0) red[wid] = mx;
  __syncthreads();
  mx = fmaxf(fmaxf(red[0], red[1]), fmaxf(red[2], red[3]));
  const float e0 = __expf(v[0] - mx), e1 = __expf(v[1] - mx);
  const float e2 = __expf(v[2] - mx), e3 = __expf(v[3] - mx);
  float s = (e0 + e1) + (e2 + e3);
#pragma unroll
  for (int off = 32; off; off >>= 1) s += __shfl_xor(s, off);
  if (lane == 0) red2[wid] = s;
  __syncthreads();
  const float inv = 1.0f / (red2[0] + red2[1] + red2[2] + red2[3]);
  u16x4 o;
  o[0] = f2bf(e0 * inv); o[1] = f2bf(e1 * inv); o[2] = f2bf(e2 * inv); o[3] = f2bf(e3 * inv);
  ((u16x4*)(Attn + (size_t)blockIdx.x * 1024))[tid] = o;
}

// ---------------- launch ----------------
// Shapes: S=1024, B=32, H=1024, T=512.
//   q'  = x @ K_w            (fused f32->fp16-split convert + 2-pass fp16 GEMM; K_b dropped)
//   scr = q'[b] @ hf16[b]^T  (fp16 2-pass, 3-buf counted-vmcnt)
//   attn = softmax(scr)      (compact bf16)
//   ctx = attn[b] @ hT[b]^T  (bf16, 2-buf, 1-barrier/K-tile)
//   out = sigmoid(ctx @ V_w^T + V_b)
// ws (MB): hf16 0-64 (attn reuses 0-32) | hT 64-128 | qhi 128-160 (ctx reuses) |
//          qlo 160-192 | scores f32 192-256 | kwT 256-258 | vw 258-260
extern "C" void kernel_launch(void* const* d_in, const int* in_sizes, int n_in,
                              void* d_out, int out_size, void* d_ws, size_t ws_size,
                              hipStream_t stream) {
  const float* hidden = (const float*)d_in[0];
  const float* x = (const float*)d_in[1];
  // d_in[2] problem_q unused; d_in[4] K_b dropped (softmax shift invariance)
  const float* K_w = (const float*)d_in[3];
  const float* V_w = (const float*)d_in[5];
  const float* V_b = (const float*)d_in[6];

  char* ws = (char*)d_ws;
  u16* hf16 = (u16*)(ws);
  u16* hT = (u16*)(ws + 67108864);
  u16* qhi = (u16*)(ws + 134217728);
  u16* qlo = (u16*)(ws + 167772160);
  float* scoresF = (float*)(ws + 201326592);
  u16* attn = hf16;  // reuse (hf16 dead after scores)
  u16* ctx = qhi;    // reuse (q' dead after scores)
  u16* kwT = (u16*)(ws + 268435456);
  u16* vw = kwT + 1024 * 1024;
  float* out = (float*)d_out;

  // 1. hidden [S,B,H] -> fp16 [B,S,H] + transposed bf16 [B,H,S]
  cvt_hidden2_k<<<dim3(16, 8, 32), 512, 0, stream>>>(hidden, hf16, hT);
  // 2. weights: K_w transposed fp16, V_w bf16
  cvt_w_t_h_k<<<dim3(16, 16), 256, 0, stream>>>(K_w, kwT);
  cvt_f32_bf16_k<<<1024, 256, 0, stream>>>(V_w, vw, 1024L * 1024 / 4);
  // 3. q' = x @ K_w  (x f32 consumed directly; split done in-kernel)
  gemm_qp_k<<<256, 512, 0, stream>>>(x, kwT, qhi, qlo);
  // 4. scores[b] = q'[b] @ hf16[b]^T
  gemm_sc_k<<<256, 512, 0, stream>>>(qhi, qlo, hf16, scoresF);
  // 5. softmax over S -> compact bf16 attn
  softmax_k<<<16384, 256, 0, stream>>>(scoresF, attn);
  // 6. ctx[b] = attn[b] @ hT[b]^T
  gemm1_8ph_k<0><<<256, 512, 0, stream>>>(attn, hT, nullptr, ctx);
  // 7. out = sigmoid(ctx @ V_w^T + V_b)
  gemm1_8ph_k<1><<<256, 512, 0, stream>>>(ctx, vw, V_b, out);
}